// Round 2
// baseline (262.670 us; speedup 1.0000x reference)
//
#include <hip/hip_runtime.h>
#include <hip/hip_bf16.h>

// Problem constants (match reference setup_inputs)
#define BATCH 4096
#define P     64
#define L     1024     // floats per (b,p) block = 4 KiB
#define LT    256      // samples per block
#define NPAIRS (BATCH * P)   // 262144

// One workgroup of 256 threads processes one (b,p) pair per loop iteration:
//  1. stage the 4 KiB dense block into LDS with coalesced float4 loads
//     (at 64B line granularity ~98% of the block is fetched anyway for 256
//      uniform-random indices, so staging costs ~nothing extra and makes
//      every HBM read coalesced)
//  2. gather LT=256 elements from LDS (random ds_read_b32, ~2-way bank
//     aliasing which is free on gfx950)
//  3. coalesced dword store of the 1 KiB output slice
// The next pair's float4 load is issued BEFORE the gather/store so HBM
// latency hides under the tail of the current iteration.
__global__ __launch_bounds__(256, 2)
void HardSamplingLayer_5360119186055_kernel(const float* __restrict__ x,
                                            const int* __restrict__ w,
                                            float* __restrict__ out) {
    __shared__ float tile[L];
    __shared__ int   widx[LT];

    const int t = threadIdx.x;            // 0..255
    widx[t] = w[t];                       // int32 per harness spec; visible after first barrier

    int pair = blockIdx.x;
    if (pair >= NPAIRS) return;

    // prefetch first block
    float4 v = ((const float4*)(x + (size_t)pair * L))[t];

    while (pair < NPAIRS) {
        __syncthreads();                  // previous gather done; widx visible
        ((float4*)tile)[t] = v;           // conflict-free ds_write_b128
        __syncthreads();

        const int next = pair + gridDim.x;
        if (next < NPAIRS) {
            // issue next block's load early; its s_waitcnt lands at the
            // tile store of the NEXT iteration, after gather+store below
            v = ((const float4*)(x + (size_t)next * L))[t];
        }

        // gather + coalesced store (64 lanes x 4B = full lines)
        out[(size_t)pair * LT + t] = tile[widx[t]];

        pair = next;
    }
}

extern "C" void kernel_launch(void* const* d_in, const int* in_sizes, int n_in,
                              void* d_out, int out_size, void* d_ws, size_t ws_size,
                              hipStream_t stream) {
    const float* x = (const float*)d_in[0];
    const int*   w = (const int*)d_in[1];   // integer input -> const int* (harness spec)
    float*     out = (float*)d_out;

    // 4096 blocks: 262144 pairs / 4096 = 64 iterations per block, exact
    // division so every block runs the same trip count (uniform branches).
    dim3 grid(4096), block(256);
    hipLaunchKernelGGL(HardSamplingLayer_5360119186055_kernel,
                       grid, block, 0, stream, x, w, out);
}